// Round 6
// baseline (210.881 us; speedup 1.0000x reference)
//
#include <hip/hip_runtime.h>
#include <math.h>

#define NB 32              // batch
#define HW (1024 * 1024)   // pixels per image
#define BINS 64            // MAX_INST
#define KLBL 64            // labels per image
#define NCLS 8             // lesion classes
#define BPI 64             // blocks per image for histogram
#define TPB 256
#define CHUNK4 4096        // int4 per block chunk (64 KB contiguous)

// ---------------------------------------------------------------------------
// Ballot-slice histogram — NO LDS/DS ops in the hot loop.
// Lane i of each wave owns bin i (64 bins == 64 lanes). Per round, each lane
// supplies one 6-bit pixel value; 6 ballots give wave-uniform per-bit masks
// b_k; lane i computes m = AND_k (b_k ^ ns_k) where ns_k = (lane bit k set ?
// 0 : ~0), i.e. the set of lanes whose value == i, and adds popcount(m).
// Rounds 2-5 proved LDS-atomic consumers are NOT the limiter but their
// vmcnt/lgkmcnt coupling in the loop is the last consumer-side suspect —
// this removes it entirely: the loop is pure VMEM + VALU.
// ---------------------------------------------------------------------------
typedef int v4i __attribute__((ext_vector_type(4)));

__global__ __launch_bounds__(TPB, 8) void hist_kernel(const int* __restrict__ mask,
                                                      int* __restrict__ hist) {
    __shared__ int sh[4][BINS];
    const int tid = threadIdx.x;
    const int lane = tid & 63;
    const int wave = tid >> 6;
    const int b = blockIdx.x / BPI;
    const int part = blockIdx.x % BPI;

    // ns_k: complement-select masks for this lane's bin (= lane id)
    unsigned long long ns[6];
    #pragma unroll
    for (int k = 0; k < 6; ++k)
        ns[k] = ((lane >> k) & 1) ? 0ULL : ~0ULL;

    const v4i* __restrict__ p4 =
        (const v4i*)(mask + (size_t)b * HW) + (size_t)part * CHUNK4;

    unsigned cnt = 0;
    #pragma unroll
    for (int h = 0; h < 4; ++h) {
        v4i v[4];
        #pragma unroll
        for (int k = 0; k < 4; ++k)
            v[k] = p4[(h * 4 + k) * TPB + tid];    // dense, 4 KB-spaced wave reqs
        #pragma unroll
        for (int k = 0; k < 4; ++k) {
            #pragma unroll
            for (int c = 0; c < 4; ++c) {
                int val = v[k][c];
                unsigned long long m = ~0ULL;
                #pragma unroll
                for (int bit = 0; bit < 6; ++bit) {
                    unsigned long long bb = __ballot(((val >> bit) & 1) != 0);
                    m &= bb ^ ns[bit];
                }
                cnt += (unsigned)__popcll(m);
            }
        }
    }

    sh[wave][lane] = (int)cnt;   // unique slot per (wave,lane): no atomic
    __syncthreads();
    if (tid < BINS) {
        int s = sh[0][tid] + sh[1][tid] + sh[2][tid] + sh[3][tid];
        atomicAdd(&hist[b * BINS + tid], s);
    }
}

// ---------------------------------------------------------------------------
// Finalize (unchanged known-good): gather sizes via label_gt (int32 pairs),
// scatter into per-class counts, clamp/100, BCE-with-logits, mean -> out[0].
// ---------------------------------------------------------------------------
__global__ __launch_bounds__(TPB) void finalize_kernel(const float* __restrict__ pred,
                                                       const int* __restrict__ lg,
                                                       const int* __restrict__ hist,
                                                       float* __restrict__ out) {
    __shared__ float cnts[NB * NCLS];
    __shared__ float wsum[4];
    const int tid = threadIdx.x;

    cnts[tid] = 0.0f;
    __syncthreads();

    for (int e = tid; e < NB * KLBL; e += TPB) {
        int inst  = lg[e * 2 + 0];
        int label = lg[e * 2 + 1];
        if (label > 0 && label <= NCLS) {
            float sz = (float)hist[(e >> 6) * BINS + (inst & 63)];
            atomicAdd(&cnts[(e >> 6) * NCLS + (label - 1)], sz);
        }
    }
    __syncthreads();

    float x = pred[tid];
    float t = fminf(cnts[tid] * (1.0f / 100.0f), 1.0f);
    float l = fmaxf(x, 0.0f) - x * t + log1pf(expf(-fabsf(x)));

    for (int off = 32; off > 0; off >>= 1)
        l += __shfl_down(l, off, 64);
    if ((tid & 63) == 0) wsum[tid >> 6] = l;
    __syncthreads();
    if (tid == 0)
        out[0] = (wsum[0] + wsum[1] + wsum[2] + wsum[3]) * (1.0f / (NB * NCLS));
}

extern "C" void kernel_launch(void* const* d_in, const int* in_sizes, int n_in,
                              void* d_out, int out_size, void* d_ws, size_t ws_size,
                              hipStream_t stream) {
    const float* pred = (const float*)d_in[0];    // [32, 8] fp32
    const int*   mask = (const int*)d_in[1];      // [32, 1024, 1024] int32
    const int*   lg   = (const int*)d_in[2];      // [32, 64, 2] delivered as int32
    float* out = (float*)d_out;
    int* hist = (int*)d_ws;                       // [32][64] int32 = 8 KB

    hipMemsetAsync(hist, 0, NB * BINS * sizeof(int), stream);
    hist_kernel<<<NB * BPI, TPB, 0, stream>>>(mask, hist);
    finalize_kernel<<<1, TPB, 0, stream>>>(pred, lg, hist, out);
}

// Round 7
// 205.546 us; speedup vs baseline: 1.0260x; 1.0260x over previous
//
#include <hip/hip_runtime.h>
#include <math.h>

#define NB 32              // batch
#define HW (1024 * 1024)   // pixels per image
#define BINS 64            // MAX_INST
#define KLBL 64            // labels per image
#define NCLS 8             // lesion classes
#define BPI 64             // blocks per image for histogram
#define TPB 256
#define CHUNK4 4096        // int4 per block chunk (64 KB contiguous)
#define NXCD 8

// ---------------------------------------------------------------------------
// Histogram (round-5 structure = best so far) + XCD-contiguous chunk map.
// Blocks dispatch round-robin across 8 XCDs; remapping chunk id so all
// blocks on one XCD stream ONE contiguous 16.8 MB region gives each per-XCD
// L2 a clean sequential stream (no interleaved holes), max row locality.
//  - contiguous 64 KB chunk per block, 4 KB-spaced wave requests
//  - loads batched 8x int4 into registers before any LDS traffic
//  - per-wave 64-bin LDS sub-histograms (proven non-limiting, cheapest)
// ---------------------------------------------------------------------------
__global__ __launch_bounds__(TPB) void hist_kernel(const int* __restrict__ mask,
                                                   int* __restrict__ hist) {
    __shared__ int sh[4][BINS];
    const int tid = threadIdx.x;
    const int wave = tid >> 6;

    // XCD-contiguous remap: blocks with the same (blockIdx % 8) — i.e. on the
    // same XCD — cover consecutive chunks.
    const int c = (blockIdx.x & (NXCD - 1)) * (NB * BPI / NXCD) + (blockIdx.x >> 3);
    const int b = c / BPI;
    const int part = c % BPI;

    sh[tid >> 6][tid & 63] = 0;   // 256 threads cover 4*64
    __syncthreads();

    const int4* __restrict__ p4 =
        (const int4*)(mask + (size_t)b * HW) + (size_t)part * CHUNK4;

    #pragma unroll
    for (int h = 0; h < 2; ++h) {
        int4 v[8];
        #pragma unroll
        for (int k = 0; k < 8; ++k)
            v[k] = p4[(h * 8 + k) * TPB + tid];   // wave req k: 4 KB apart, dense
        #pragma unroll
        for (int k = 0; k < 8; ++k) {
            atomicAdd(&sh[wave][v[k].x & 63], 1);
            atomicAdd(&sh[wave][v[k].y & 63], 1);
            atomicAdd(&sh[wave][v[k].z & 63], 1);
            atomicAdd(&sh[wave][v[k].w & 63], 1);
        }
    }
    __syncthreads();

    if (tid < BINS) {
        int s = sh[0][tid] + sh[1][tid] + sh[2][tid] + sh[3][tid];
        atomicAdd(&hist[b * BINS + tid], s);
    }
}

// ---------------------------------------------------------------------------
// Finalize (unchanged known-good): gather sizes via label_gt (int32 pairs),
// scatter into per-class counts, clamp/100, BCE-with-logits, mean -> out[0].
// ---------------------------------------------------------------------------
__global__ __launch_bounds__(TPB) void finalize_kernel(const float* __restrict__ pred,
                                                       const int* __restrict__ lg,
                                                       const int* __restrict__ hist,
                                                       float* __restrict__ out) {
    __shared__ float cnts[NB * NCLS];
    __shared__ float wsum[4];
    const int tid = threadIdx.x;

    cnts[tid] = 0.0f;
    __syncthreads();

    for (int e = tid; e < NB * KLBL; e += TPB) {
        int inst  = lg[e * 2 + 0];
        int label = lg[e * 2 + 1];
        if (label > 0 && label <= NCLS) {
            float sz = (float)hist[(e >> 6) * BINS + (inst & 63)];
            atomicAdd(&cnts[(e >> 6) * NCLS + (label - 1)], sz);
        }
    }
    __syncthreads();

    float x = pred[tid];
    float t = fminf(cnts[tid] * (1.0f / 100.0f), 1.0f);
    float l = fmaxf(x, 0.0f) - x * t + log1pf(expf(-fabsf(x)));

    for (int off = 32; off > 0; off >>= 1)
        l += __shfl_down(l, off, 64);
    if ((tid & 63) == 0) wsum[tid >> 6] = l;
    __syncthreads();
    if (tid == 0)
        out[0] = (wsum[0] + wsum[1] + wsum[2] + wsum[3]) * (1.0f / (NB * NCLS));
}

extern "C" void kernel_launch(void* const* d_in, const int* in_sizes, int n_in,
                              void* d_out, int out_size, void* d_ws, size_t ws_size,
                              hipStream_t stream) {
    const float* pred = (const float*)d_in[0];    // [32, 8] fp32
    const int*   mask = (const int*)d_in[1];      // [32, 1024, 1024] int32
    const int*   lg   = (const int*)d_in[2];      // [32, 64, 2] delivered as int32
    float* out = (float*)d_out;
    int* hist = (int*)d_ws;                       // [32][64] int32 = 8 KB

    hipMemsetAsync(hist, 0, NB * BINS * sizeof(int), stream);
    hist_kernel<<<NB * BPI, TPB, 0, stream>>>(mask, hist);
    finalize_kernel<<<1, TPB, 0, stream>>>(pred, lg, hist, out);
}